// Round 12
// baseline (34.913 us; speedup 1.0000x reference)
//
#include <hip/hip_runtime.h>
#include <math.h>

#define NPTS   2048
#define BATCH  32
#define GPB    2
#define NSPLIT 16            // 2048 / (64*GPB)
#define M_POLY 815
#define QSTR   160           // Q words per point row (5 x 32-word frames)
#define T0OFF  10240         // 64*160; T0col[16][64]
#define SCROFF 11264         // combine scratch: 1024 + 16 floats
#define BN_EPS 1e-5f

// chunk ci -> (L=e1+e2, k0=e2 block start, c=e0, qoff4=word offset of Q quad)
__device__ __forceinline__ bool decode_chunk(int ci, int& Lo, int& k0o, int& co, int& qo) {
    int idx = 0, qoff = 0;
    for (int l = 0; l < 16; ++l) {
        const int nb   = (l + 4) >> 2;
        const int cmin = (l == 0) ? 1 : 0;
        const int nc   = 16 - l - cmin;
        for (int kb = 0; kb < nb; ++kb) {
            if (ci < idx + nc) {
                Lo = l; k0o = kb * 4; co = cmin + (ci - idx);
                qo = qoff + kb * 4;
                return true;
            }
            idx += nc;
        }
        qoff += nb * 4;
    }
    return false;
}

// ---------------------------------------------------------------------------
// Moments kernel. grid (16, 32), block 512 (8 waves). Same table math as R9;
// phase A split across 8 waves; phase B: thread (tt=t&255, hh=t>>8) covers
// chunk tt over points [hh*32, hh*32+32); halves combined via LDS scratch.
// TLP: 16-24 waves/CU (vs 8 in R9) to hide the ds_read_b128 latency chain.
// ---------------------------------------------------------------------------
__global__ __launch_bounds__(512) void moments_kernel(
    const float* __restrict__ x,      // (B, 3, N)
    float*       __restrict__ part)   // (B, NSPLIT, M_POLY)
{
    __shared__ __align__(16) float P[12304];   // 49,216 B -> up to 3 blocks/CU
    const int t  = threadIdx.x;
    const int sb = blockIdx.x;
    const int b  = blockIdx.y;
    const int tt = t & 255;       // chunk id
    const int hh = t >> 8;        // point half
    const int nn = t & 63;        // phase-A point
    const int qq = t >> 6;        // phase-A slice (0..7)
    const int sw = 4 * (nn & 7);
    const int base = nn * QSTR;

    int L, k0, c, qoff4;
    decode_chunk(tt, L, k0, c, qoff4);
    // leftover chunks 256..258 = (L=15, c=0, k0=4/8/12) on lanes 253..255
    const bool dual = (tt >= 253);
    const int k02   = dual ? 4 * (tt - 252) : 4;
    const int qoff42 = 144 + k02;            // Qoff(L=15)=144

    int qx[8], q2x[8];
    #pragma unroll
    for (int r = 0; r < 8; ++r) {
        qx[r]  = qoff4  ^ (4 * r);
        q2x[r] = qoff42 ^ (4 * r);
    }

    float a[4]  = {0.f, 0.f, 0.f, 0.f};
    float a2[4] = {0.f, 0.f, 0.f, 0.f};
    const float* xb = x + (size_t)b * 3 * NPTS;

    for (int g = 0; g < GPB; ++g) {
        if (g) __syncthreads();
        {   // ---------------- phase A (8-wave split) ----------------
            const int n = (sb * GPB + g) * 64 + nn;
            const float x1 = xb[NPTS + n], x2 = xb[2 * NPTS + n];
            float T1r[16], T2r[16];
            T1r[0] = 1.f; T1r[1] = x1;
            #pragma unroll
            for (int k = 2; k < 16; ++k) T1r[k] = 2.f * x1 * T1r[k-1] - T1r[k-2];
            T2r[0] = 1.f; T2r[1] = x2;
            #pragma unroll
            for (int k = 2; k < 16; ++k) T2r[k] = 2.f * x2 * T2r[k-1] - T2r[k-2];

            #define QVAL(SS,E) (((E) <= (SS)) ? T1r[((SS)-(E)) & 15] * T2r[(E) & 15] : 0.f)
            #define ROWQ(SS, QO) { \
                _Pragma("unroll") \
                for (int blk2 = 0; blk2 < ((SS)+4)/4; ++blk2) { \
                    float4 v; \
                    v.x = QVAL(SS, 4*blk2+0); v.y = QVAL(SS, 4*blk2+1); \
                    v.z = QVAL(SS, 4*blk2+2); v.w = QVAL(SS, 4*blk2+3); \
                    *(float4*)&P[base + (((QO) + 4*blk2) ^ sw)] = v; } }

            if (qq == 0) {
                const float x0 = xb[n];
                float T0r[16];
                T0r[0] = 1.f; T0r[1] = x0;
                #pragma unroll
                for (int k = 2; k < 16; ++k) T0r[k] = 2.f * x0 * T0r[k-1] - T0r[k-2];
                #pragma unroll
                for (int cc = 0; cc < 16; ++cc)
                    P[T0OFF + cc * 64 + ((nn + 4 * cc) & 63)] = T0r[cc];
                ROWQ(0, 0)
            } else if (qq == 1) {
                ROWQ(1, 4)   ROWQ(2, 8)   ROWQ(3, 12)
            } else if (qq == 2) {
                ROWQ(4, 16)  ROWQ(5, 24)
            } else if (qq == 3) {
                ROWQ(6, 32)  ROWQ(7, 40)
            } else if (qq == 4) {
                ROWQ(8, 48)  ROWQ(9, 60)
            } else if (qq == 5) {
                ROWQ(10, 72) ROWQ(11, 84)
            } else if (qq == 6) {
                ROWQ(12, 96) ROWQ(13, 112)
            } else {
                ROWQ(14, 128) ROWQ(15, 144)
            }
            #undef ROWQ
            #undef QVAL
        }
        __syncthreads();

        // ---------------- phase B: 32 points per thread ----------------
        #pragma unroll 4
        for (int q4 = 0; q4 < 8; ++q4) {
            const int np0 = hh * 32 + q4 * 4;
            const float4 t0q =
                *(const float4*)&P[T0OFF + c * 64 + ((np0 + 4 * c) & 63)];
            #pragma unroll
            for (int i = 0; i < 4; ++i) {
                const int np = np0 + i;
                const float* rp = &P[np * QSTR];
                const float  t0v = ((const float*)&t0q)[i];
                const float4 qv = *(const float4*)&rp[qx[np & 7]];
                a[0] = fmaf(t0v, qv.x, a[0]);
                a[1] = fmaf(t0v, qv.y, a[1]);
                a[2] = fmaf(t0v, qv.z, a[2]);
                a[3] = fmaf(t0v, qv.w, a[3]);
                if (dual) {           // e0=0 -> T0 = 1, Q-only accumulate
                    const float4 p2 = *(const float4*)&rp[q2x[np & 7]];
                    a2[0] += p2.x; a2[1] += p2.y; a2[2] += p2.z; a2[3] += p2.w;
                }
            }
        }
    }

    // ---------------- combine halves, store ----------------
    __syncthreads();
    if (hh == 1) {
        #pragma unroll
        for (int i = 0; i < 4; ++i) P[SCROFF + tt * 4 + i] = a[i];
        if (dual) {
            #pragma unroll
            for (int i = 0; i < 4; ++i) P[SCROFF + 1024 + (tt - 253) * 4 + i] = a2[i];
        }
    }
    __syncthreads();
    if (hh == 0) {
        float* pb = part + ((size_t)b * NSPLIT + sb) * M_POLY;
        {
            const int D  = c + L;
            const int mb = D * (D + 1) * (D + 2) / 6 - 1 + L * (L + 1) / 2;
            const int nv = (L - k0 + 1 < 4) ? (L - k0 + 1) : 4;
            #pragma unroll
            for (int i = 0; i < 4; ++i)
                if (i < nv) pb[mb + k0 + i] = a[i] + P[SCROFF + tt * 4 + i];
        }
        if (dual) {
            const int mb = 799;          // D=15, L=15 base
            #pragma unroll
            for (int i = 0; i < 4; ++i)
                pb[mb + k02 + i] = a2[i] + P[SCROFF + 1024 + (tt - 253) * 4 + i];
        }
    }
}

// ---------------------------------------------------------------------------
// Layer 1: reduce partials + 815->512 + BN + ReLU, TWO batches per block.
// grid = (8, 16), block 512 = 64 outputs x 8 k-groups; W1 read once/2 batches.
// ---------------------------------------------------------------------------
__global__ __launch_bounds__(512) void l1_kernel(
    const float* __restrict__ part,
    const float* __restrict__ W1, const float* __restrict__ b1,
    const float* __restrict__ g1, const float* __restrict__ be1,
    const float* __restrict__ rm1, const float* __restrict__ rv1,
    float* __restrict__ h1)
{
    __shared__ float fs0[816], fs1[816];
    __shared__ float red[8][64][2];
    const int t  = threadIdx.x;
    const int og = blockIdx.x;
    const int b0 = blockIdx.y * 2;
    const int b1i = b0 + 1;

    {
        float s0 = 0.f, s1 = 0.f;
        #pragma unroll
        for (int sp = 0; sp < NSPLIT; ++sp) {
            s0 += part[((size_t)b0 * NSPLIT + sp) * M_POLY + t];
            s1 += part[((size_t)b1i * NSPLIT + sp) * M_POLY + t];
        }
        fs0[t] = s0 * (1.0f / (float)NPTS);
        fs1[t] = s1 * (1.0f / (float)NPTS);
        if (t < 303) {
            float u0 = 0.f, u1 = 0.f;
            #pragma unroll
            for (int sp = 0; sp < NSPLIT; ++sp) {
                u0 += part[((size_t)b0 * NSPLIT + sp) * M_POLY + 512 + t];
                u1 += part[((size_t)b1i * NSPLIT + sp) * M_POLY + 512 + t];
            }
            fs0[512 + t] = u0 * (1.0f / (float)NPTS);
            fs1[512 + t] = u1 * (1.0f / (float)NPTS);
        }
        if (t == 0) { fs0[815] = 0.f; fs1[815] = 0.f; }
    }
    __syncthreads();

    const int o  = og * 64 + (t & 63);
    const int cg = t >> 6;
    const int kb = cg * 102;               // 8*102 = 816; fs[815]=0 nulls pad
    float acc0 = 0.f, acc1 = 0.f;
    #pragma unroll 6
    for (int kk = 0; kk < 102; ++kk) {
        const int k  = kb + kk;
        const int kr = (k < 815) ? k : 814;
        const float w = W1[(size_t)kr * 512 + o];
        acc0 = fmaf(fs0[k], w, acc0);
        acc1 = fmaf(fs1[k], w, acc1);
    }
    red[cg][t & 63][0] = acc0;
    red[cg][t & 63][1] = acc1;
    __syncthreads();

    if (t < 128) {
        const int lane  = t & 63;
        const int which = t >> 6;
        float dot = 0.f;
        #pragma unroll
        for (int j = 0; j < 8; ++j) dot += red[j][lane][which];
        const int oo = og * 64 + lane;
        const int bb = b0 + which;
        const float v = (dot + b1[oo] - rm1[oo]) * g1[oo] * rsqrtf(rv1[oo] + BN_EPS) + be1[oo];
        h1[bb * 512 + oo] = v > 0.f ? v : 0.f;
    }
}

// ---------------------------------------------------------------------------
// Layer 2 — byte-identical to R9. grid (8, 32), block 512 = 32 o x 16 kg.
// ---------------------------------------------------------------------------
__global__ __launch_bounds__(512) void l2_kernel(
    const float* __restrict__ h1,
    const float* __restrict__ W2, const float* __restrict__ b2,
    const float* __restrict__ g2, const float* __restrict__ be2,
    const float* __restrict__ rm2, const float* __restrict__ rv2,
    float* __restrict__ h2)
{
    __shared__ float hs[512];
    __shared__ float red[16][32];
    const int t  = threadIdx.x;
    const int og = blockIdx.x;
    const int b  = blockIdx.y;

    hs[t] = h1[b * 512 + t];
    __syncthreads();

    const int o  = og * 32 + (t & 31);
    const int cg = t >> 5;
    const int kb = cg * 32;
    float acc = 0.f;
    #pragma unroll
    for (int kk = 0; kk < 32; ++kk)
        acc = fmaf(hs[kb + kk], W2[(size_t)(kb + kk) * 256 + o], acc);
    red[cg][t & 31] = acc;
    __syncthreads();

    if (t < 32) {
        float dot = 0.f;
        #pragma unroll
        for (int j = 0; j < 16; ++j) dot += red[j][t];
        const int oo = og * 32 + t;
        const float v = (dot + b2[oo] - rm2[oo]) * g2[oo] * rsqrtf(rv2[oo] + BN_EPS) + be2[oo];
        h2[b * 256 + oo] = v > 0.f ? v : 0.f;
    }
}

// ---------------------------------------------------------------------------
// Layers 3+4 — byte-identical to R9. grid = 32, block 512.
// ---------------------------------------------------------------------------
__global__ __launch_bounds__(512) void l34_kernel(
    const float* __restrict__ h2,
    const float* __restrict__ W3, const float* __restrict__ b3,
    const float* __restrict__ g3, const float* __restrict__ be3,
    const float* __restrict__ rm3, const float* __restrict__ rv3,
    const float* __restrict__ W4, const float* __restrict__ b4,
    float* __restrict__ out)
{
    __shared__ float hs[256];
    __shared__ float red3[4][128];
    __shared__ float h3s[128];
    __shared__ float red4[8][64];
    const int t = threadIdx.x;
    const int b = blockIdx.x;

    if (t < 256) hs[t] = h2[b * 256 + t];
    __syncthreads();

    {
        const int o  = t & 127;
        const int cg = t >> 7;
        const int kb = cg * 64;
        float acc = 0.f;
        #pragma unroll 8
        for (int kk = 0; kk < 64; ++kk)
            acc = fmaf(hs[kb + kk], W3[(size_t)(kb + kk) * 128 + o], acc);
        red3[cg][o] = acc;
    }
    __syncthreads();
    if (t < 128) {
        const float dot = red3[0][t] + red3[1][t] + red3[2][t] + red3[3][t];
        const float v = (dot + b3[t] - rm3[t]) * g3[t] * rsqrtf(rv3[t] + BN_EPS) + be3[t];
        h3s[t] = v > 0.f ? v : 0.f;
    }
    __syncthreads();

    {
        const int o  = t & 63;
        const int om = (o < 40) ? o : 39;
        const int cg = t >> 6;
        const int kb = cg * 16;
        float acc = 0.f;
        #pragma unroll
        for (int kk = 0; kk < 16; ++kk)
            acc = fmaf(h3s[kb + kk], W4[(size_t)(kb + kk) * 40 + om], acc);
        red4[cg][o] = acc;
    }
    __syncthreads();
    if (t < 40) {
        float dot = 0.f;
        #pragma unroll
        for (int j = 0; j < 8; ++j) dot += red4[j][t];
        out[b * 40 + t] = dot + b4[t];
    }
}

extern "C" void kernel_launch(void* const* d_in, const int* in_sizes, int n_in,
                              void* d_out, int out_size, void* d_ws, size_t ws_size,
                              hipStream_t stream) {
    const float* x  = (const float*)d_in[0];
    const float* W1 = (const float*)d_in[2];
    const float* b1 = (const float*)d_in[3];
    const float* g1 = (const float*)d_in[4];
    const float* be1= (const float*)d_in[5];
    const float* rm1= (const float*)d_in[6];
    const float* rv1= (const float*)d_in[7];
    const float* W2 = (const float*)d_in[8];
    const float* b2 = (const float*)d_in[9];
    const float* g2 = (const float*)d_in[10];
    const float* be2= (const float*)d_in[11];
    const float* rm2= (const float*)d_in[12];
    const float* rv2= (const float*)d_in[13];
    const float* W3 = (const float*)d_in[14];
    const float* b3 = (const float*)d_in[15];
    const float* g3 = (const float*)d_in[16];
    const float* be3= (const float*)d_in[17];
    const float* rm3= (const float*)d_in[18];
    const float* rv3= (const float*)d_in[19];
    const float* W4 = (const float*)d_in[20];
    const float* b4 = (const float*)d_in[21];
    float* out = (float*)d_out;

    float* part = (float*)d_ws;                              // 32*16*815 f32
    float* h1   = part + (size_t)BATCH * NSPLIT * M_POLY;    // 32*512
    float* h2   = h1 + (size_t)BATCH * 512;                  // 32*256

    moments_kernel<<<dim3(NSPLIT, BATCH), 512, 0, stream>>>(x, part);
    l1_kernel<<<dim3(8, BATCH / 2), 512, 0, stream>>>(part,
        W1, b1, g1, be1, rm1, rv1, h1);
    l2_kernel<<<dim3(8, BATCH), 512, 0, stream>>>(h1,
        W2, b2, g2, be2, rm2, rv2, h2);
    l34_kernel<<<BATCH, 512, 0, stream>>>(h2,
        W3, b3, g3, be3, rm3, rv3, W4, b4, out);
}

// Round 13
// 31.930 us; speedup vs baseline: 1.0934x; 1.0934x over previous
//
#include <hip/hip_runtime.h>
#include <math.h>

#define NPTS   2048
#define BATCH  32
#define M_POLY 815
#define GPB    2
#define NSPLIT 16            // 2048 / (64*GPB)
#define QSTR   160           // Q words per point row (5 x 32-word frames)
#define T0OFF  10240         // 64*160; T0col[16][64] lives here (+1024 words)
#define BN_EPS 1e-5f

// chunk ci -> (L=e1+e2, k0=e2 block start, c=e0, qoff4=word offset of Q quad)
// ordering: L-major, then k0-block, then c => wave-mates share the quad addr.
__device__ __forceinline__ bool decode_chunk(int ci, int& Lo, int& k0o, int& co, int& qo) {
    int idx = 0, qoff = 0;
    for (int l = 0; l < 16; ++l) {
        const int nb   = (l + 4) >> 2;
        const int cmin = (l == 0) ? 1 : 0;
        const int nc   = 16 - l - cmin;
        for (int kb = 0; kb < nb; ++kb) {
            if (ci < idx + nc) {
                Lo = l; k0o = kb * 4; co = cmin + (ci - idx);
                qo = qoff + kb * 4;
                return true;
            }
            idx += nc;
        }
        qoff += nb * 4;
    }
    return false;
}

// ---------------------------------------------------------------------------
// Moments kernel — measured-best config (R9/R11, 31.9 µs total): grid
// (16, 32), block 256, GPB=2, 2 blocks/CU (45 KB LDS), phase-B unroll 8.
// ---------------------------------------------------------------------------
__global__ __launch_bounds__(256) void moments_kernel(
    const float* __restrict__ x,      // (B, 3, N)
    float*       __restrict__ part)   // (B, NSPLIT, M_POLY)
{
    __shared__ __align__(16) float P[64 * QSTR + 1024];   // 45,056 B
    const int t  = threadIdx.x;
    const int sb = blockIdx.x;
    const int b  = blockIdx.y;
    const int nn = t & 63;
    const int qq = t >> 6;
    const int sw = 4 * (nn & 7);
    const int base = nn * QSTR;

    int L, k0, c, qoff4;
    decode_chunk(t, L, k0, c, qoff4);
    // leftover chunks 256..258 = (L=15, c=0, k0=4/8/12) on lanes 253..255
    const bool dual = (t >= 253);
    const int k02   = dual ? 4 * (t - 252) : 4;
    const int qoff42 = 144 + k02;            // Qoff(L=15)=144

    int qx[8], q2x[8];
    #pragma unroll
    for (int r = 0; r < 8; ++r) {
        qx[r]  = qoff4  ^ (4 * r);
        q2x[r] = qoff42 ^ (4 * r);
    }

    float a[4]  = {0.f, 0.f, 0.f, 0.f};
    float a2[4] = {0.f, 0.f, 0.f, 0.f};
    const float* xb = x + (size_t)b * 3 * NPTS;

    for (int g = 0; g < GPB; ++g) {
        if (g) __syncthreads();
        {   // ---------------- phase A ----------------
            const int n = (sb * GPB + g) * 64 + nn;
            const float x1 = xb[NPTS + n], x2 = xb[2 * NPTS + n];
            float T1r[16], T2r[16];
            T1r[0] = 1.f; T1r[1] = x1;
            #pragma unroll
            for (int k = 2; k < 16; ++k) T1r[k] = 2.f * x1 * T1r[k-1] - T1r[k-2];
            T2r[0] = 1.f; T2r[1] = x2;
            #pragma unroll
            for (int k = 2; k < 16; ++k) T2r[k] = 2.f * x2 * T2r[k-1] - T2r[k-2];

            #define QVAL(SS,E) (((E) <= (SS)) ? T1r[((SS)-(E)) & 15] * T2r[(E) & 15] : 0.f)
            #define ROWQ(SS, QO) { \
                _Pragma("unroll") \
                for (int blk2 = 0; blk2 < ((SS)+4)/4; ++blk2) { \
                    float4 v; \
                    v.x = QVAL(SS, 4*blk2+0); v.y = QVAL(SS, 4*blk2+1); \
                    v.z = QVAL(SS, 4*blk2+2); v.w = QVAL(SS, 4*blk2+3); \
                    *(float4*)&P[base + (((QO) + 4*blk2) ^ sw)] = v; } }

            if (qq == 0) {
                const float x0 = xb[n];
                float T0r[16];
                T0r[0] = 1.f; T0r[1] = x0;
                #pragma unroll
                for (int k = 2; k < 16; ++k) T0r[k] = 2.f * x0 * T0r[k-1] - T0r[k-2];
                #pragma unroll
                for (int cc = 0; cc < 16; ++cc)
                    P[T0OFF + cc * 64 + ((nn + 4 * cc) & 63)] = T0r[cc];
                ROWQ(0, 0)  ROWQ(1, 4)  ROWQ(2, 8)  ROWQ(3, 12)
            } else if (qq == 1) {
                ROWQ(4, 16) ROWQ(5, 24) ROWQ(6, 32) ROWQ(7, 40) ROWQ(8, 48)
            } else if (qq == 2) {
                ROWQ(9, 60) ROWQ(10, 72) ROWQ(11, 84) ROWQ(12, 96)
            } else {
                ROWQ(13, 112) ROWQ(14, 128) ROWQ(15, 144)
            }
            #undef ROWQ
            #undef QVAL
        }
        __syncthreads();

        // ---------------- phase B ----------------
        #pragma unroll 8
        for (int q4 = 0; q4 < 16; ++q4) {
            const int np0 = q4 * 4;
            const float4 t0q =
                *(const float4*)&P[T0OFF + c * 64 + ((np0 + 4 * c) & 63)];
            #pragma unroll
            for (int i = 0; i < 4; ++i) {
                const int np = np0 + i;
                const float* rp = &P[np * QSTR];
                const float  t0v = ((const float*)&t0q)[i];
                const float4 qv = *(const float4*)&rp[qx[np & 7]];
                a[0] = fmaf(t0v, qv.x, a[0]);
                a[1] = fmaf(t0v, qv.y, a[1]);
                a[2] = fmaf(t0v, qv.z, a[2]);
                a[3] = fmaf(t0v, qv.w, a[3]);
                if (dual) {           // e0=0 -> T0 = 1, Q-only accumulate
                    const float4 p2 = *(const float4*)&rp[q2x[np & 7]];
                    a2[0] += p2.x; a2[1] += p2.y; a2[2] += p2.z; a2[3] += p2.w;
                }
            }
        }
    }

    // store: m = tet(D)-1 + L(L+1)/2 + e2, consecutive in e2
    float* pb = part + ((size_t)b * NSPLIT + sb) * M_POLY;
    {
        const int D  = c + L;
        const int mb = D * (D + 1) * (D + 2) / 6 - 1 + L * (L + 1) / 2;
        const int nv = (L - k0 + 1 < 4) ? (L - k0 + 1) : 4;
        #pragma unroll
        for (int i = 0; i < 4; ++i)
            if (i < nv) pb[mb + k0 + i] = a[i];
    }
    if (dual) {
        const int mb = 799;          // D=15, L=15 base
        #pragma unroll
        for (int i = 0; i < 4; ++i)
            pb[mb + k02 + i] = a2[i];
    }
}

// ---------------------------------------------------------------------------
// Layer 1 — R9 config. grid (8, 32), block 512 = 64 o x 8 kg (chains of 102).
// ---------------------------------------------------------------------------
__global__ __launch_bounds__(512) void l1_kernel(
    const float* __restrict__ part,
    const float* __restrict__ W1, const float* __restrict__ b1,
    const float* __restrict__ g1, const float* __restrict__ be1,
    const float* __restrict__ rm1, const float* __restrict__ rv1,
    float* __restrict__ h1)
{
    __shared__ float fs[816];
    __shared__ float red[8][64];
    const int t  = threadIdx.x;
    const int og = blockIdx.x;
    const int b  = blockIdx.y;

    {
        float s0 = 0.f;
        #pragma unroll
        for (int sp = 0; sp < NSPLIT; ++sp)
            s0 += part[((size_t)b * NSPLIT + sp) * M_POLY + t];
        fs[t] = s0 * (1.0f / (float)NPTS);
        if (t < 303) {
            float s1 = 0.f;
            #pragma unroll
            for (int sp = 0; sp < NSPLIT; ++sp)
                s1 += part[((size_t)b * NSPLIT + sp) * M_POLY + 512 + t];
            fs[512 + t] = s1 * (1.0f / (float)NPTS);
        }
        if (t == 0) fs[815] = 0.f;
    }
    __syncthreads();

    const int o  = og * 64 + (t & 63);
    const int cg = t >> 6;
    const int kb = cg * 102;               // 8*102 = 816; fs[815]=0 nulls pad
    float acc = 0.f;
    #pragma unroll 6
    for (int kk = 0; kk < 102; ++kk) {
        const int k  = kb + kk;
        const int kr = (k < 815) ? k : 814;
        acc = fmaf(fs[k], W1[(size_t)kr * 512 + o], acc);
    }
    red[cg][t & 63] = acc;
    __syncthreads();

    if (t < 64) {
        float dot = 0.f;
        #pragma unroll
        for (int j = 0; j < 8; ++j) dot += red[j][t];
        const int oo = og * 64 + t;
        const float v = (dot + b1[oo] - rm1[oo]) * g1[oo] * rsqrtf(rv1[oo] + BN_EPS) + be1[oo];
        h1[b * 512 + oo] = v > 0.f ? v : 0.f;
    }
}

// ---------------------------------------------------------------------------
// Layer 2 — R9 config. grid (8, 32), block 512 = 32 o x 16 kg.
// ---------------------------------------------------------------------------
__global__ __launch_bounds__(512) void l2_kernel(
    const float* __restrict__ h1,
    const float* __restrict__ W2, const float* __restrict__ b2,
    const float* __restrict__ g2, const float* __restrict__ be2,
    const float* __restrict__ rm2, const float* __restrict__ rv2,
    float* __restrict__ h2)
{
    __shared__ float hs[512];
    __shared__ float red[16][32];
    const int t  = threadIdx.x;
    const int og = blockIdx.x;
    const int b  = blockIdx.y;

    hs[t] = h1[b * 512 + t];
    __syncthreads();

    const int o  = og * 32 + (t & 31);
    const int cg = t >> 5;
    const int kb = cg * 32;
    float acc = 0.f;
    #pragma unroll
    for (int kk = 0; kk < 32; ++kk)
        acc = fmaf(hs[kb + kk], W2[(size_t)(kb + kk) * 256 + o], acc);
    red[cg][t & 31] = acc;
    __syncthreads();

    if (t < 32) {
        float dot = 0.f;
        #pragma unroll
        for (int j = 0; j < 16; ++j) dot += red[j][t];
        const int oo = og * 32 + t;
        const float v = (dot + b2[oo] - rm2[oo]) * g2[oo] * rsqrtf(rv2[oo] + BN_EPS) + be2[oo];
        h2[b * 256 + oo] = v > 0.f ? v : 0.f;
    }
}

// ---------------------------------------------------------------------------
// Layers 3+4 — R9 config. grid = 32, block 512.
// ---------------------------------------------------------------------------
__global__ __launch_bounds__(512) void l34_kernel(
    const float* __restrict__ h2,
    const float* __restrict__ W3, const float* __restrict__ b3,
    const float* __restrict__ g3, const float* __restrict__ be3,
    const float* __restrict__ rm3, const float* __restrict__ rv3,
    const float* __restrict__ W4, const float* __restrict__ b4,
    float* __restrict__ out)
{
    __shared__ float hs[256];
    __shared__ float red3[4][128];
    __shared__ float h3s[128];
    __shared__ float red4[8][64];
    const int t = threadIdx.x;
    const int b = blockIdx.x;

    if (t < 256) hs[t] = h2[b * 256 + t];
    __syncthreads();

    {
        const int o  = t & 127;
        const int cg = t >> 7;
        const int kb = cg * 64;
        float acc = 0.f;
        #pragma unroll 8
        for (int kk = 0; kk < 64; ++kk)
            acc = fmaf(hs[kb + kk], W3[(size_t)(kb + kk) * 128 + o], acc);
        red3[cg][o] = acc;
    }
    __syncthreads();
    if (t < 128) {
        const float dot = red3[0][t] + red3[1][t] + red3[2][t] + red3[3][t];
        const float v = (dot + b3[t] - rm3[t]) * g3[t] * rsqrtf(rv3[t] + BN_EPS) + be3[t];
        h3s[t] = v > 0.f ? v : 0.f;
    }
    __syncthreads();

    {
        const int o  = t & 63;
        const int om = (o < 40) ? o : 39;
        const int cg = t >> 6;
        const int kb = cg * 16;
        float acc = 0.f;
        #pragma unroll
        for (int kk = 0; kk < 16; ++kk)
            acc = fmaf(h3s[kb + kk], W4[(size_t)(kb + kk) * 40 + om], acc);
        red4[cg][o] = acc;
    }
    __syncthreads();
    if (t < 40) {
        float dot = 0.f;
        #pragma unroll
        for (int j = 0; j < 8; ++j) dot += red4[j][t];
        out[b * 40 + t] = dot + b4[t];
    }
}

extern "C" void kernel_launch(void* const* d_in, const int* in_sizes, int n_in,
                              void* d_out, int out_size, void* d_ws, size_t ws_size,
                              hipStream_t stream) {
    const float* x  = (const float*)d_in[0];
    const float* W1 = (const float*)d_in[2];
    const float* b1 = (const float*)d_in[3];
    const float* g1 = (const float*)d_in[4];
    const float* be1= (const float*)d_in[5];
    const float* rm1= (const float*)d_in[6];
    const float* rv1= (const float*)d_in[7];
    const float* W2 = (const float*)d_in[8];
    const float* b2 = (const float*)d_in[9];
    const float* g2 = (const float*)d_in[10];
    const float* be2= (const float*)d_in[11];
    const float* rm2= (const float*)d_in[12];
    const float* rv2= (const float*)d_in[13];
    const float* W3 = (const float*)d_in[14];
    const float* b3 = (const float*)d_in[15];
    const float* g3 = (const float*)d_in[16];
    const float* be3= (const float*)d_in[17];
    const float* rm3= (const float*)d_in[18];
    const float* rv3= (const float*)d_in[19];
    const float* W4 = (const float*)d_in[20];
    const float* b4 = (const float*)d_in[21];
    float* out = (float*)d_out;

    float* part = (float*)d_ws;                              // 32*16*815 f32
    float* h1   = part + (size_t)BATCH * NSPLIT * M_POLY;    // 32*512
    float* h2   = h1 + (size_t)BATCH * 512;                  // 32*256

    moments_kernel<<<dim3(NSPLIT, BATCH), 256, 0, stream>>>(x, part);
    l1_kernel<<<dim3(8, BATCH), 512, 0, stream>>>(part,
        W1, b1, g1, be1, rm1, rv1, h1);
    l2_kernel<<<dim3(8, BATCH), 512, 0, stream>>>(h1,
        W2, b2, g2, be2, rm2, rv2, h2);
    l34_kernel<<<BATCH, 512, 0, stream>>>(h2,
        W3, b3, g3, be3, rm3, rv3, W4, b4, out);
}

// Round 14
// 31.446 us; speedup vs baseline: 1.1103x; 1.0154x over previous
//
#include <hip/hip_runtime.h>
#include <math.h>

#define NPTS   2048
#define BATCH  32
#define M_POLY 815
#define GPB    2
#define NSPLIT 16            // 2048 / (64*GPB)
#define QSTR   160           // Q words per point row (5 x 32-word frames)
#define T0OFF  10240         // 64*160; T0col[16][64] lives here (+1024 words)
#define NSLOT  140           // paired-c slots covering all 259 chunks
#define BN_EPS 1e-5f

// slot ci -> (L, k0=e2 block start, c0=first e0, npair in {1,2}, qoff4)
// pairing: within each (L, e2-block), consecutive c's share the SAME Q quad;
// one slot owns monomials (c0, L, k0..k0+3) and (c0+1, L, k0..k0+3).
__device__ __forceinline__ bool decode_pair(int ci, int& Lo, int& k0o,
                                            int& c0o, int& npo, int& qo) {
    int idx = 0, qoff = 0;
    for (int l = 0; l < 16; ++l) {
        const int nb   = (l + 4) >> 2;          // e2 blocks of 4
        const int cmin = (l == 0) ? 1 : 0;      // drop constant monomial
        const int nc   = 16 - l - cmin;         // c in [cmin, 15-l]
        const int ns   = (nc + 1) >> 1;         // c-pair slots per block
        for (int kb = 0; kb < nb; ++kb) {
            if (ci < idx + ns) {
                const int p = ci - idx;
                Lo  = l; k0o = kb * 4;
                c0o = cmin + 2 * p;
                npo = (nc - 2 * p >= 2) ? 2 : 1;
                qo  = qoff + kb * 4;
                return true;
            }
            idx += ns;
        }
        qoff += nb * 4;
    }
    Lo = 0; k0o = 0; c0o = 0; npo = 0; qo = 0;
    return false;
}

// ---------------------------------------------------------------------------
// Moments kernel. grid (16, 32), block 256, GPB=2, 2 blocks/CU (45 KB LDS).
// Phase A: identical to R11 (swizzled Q anti-diagonals + rotated T0col).
// Phase B: slot lanes t<140 each accumulate 8 monomials (two c's sharing the
// Q quad): per 4 points 2 T0col b128 + 4 Q b128 = 6 reads / 32 FMAs
// (was 5 reads / 16 FMAs) -> 0.65x wave-level LDS read instructions.
// ---------------------------------------------------------------------------
__global__ __launch_bounds__(256) void moments_kernel(
    const float* __restrict__ x,      // (B, 3, N)
    float*       __restrict__ part)   // (B, NSPLIT, M_POLY)
{
    __shared__ __align__(16) float P[64 * QSTR + 1024];   // 45,056 B
    const int t  = threadIdx.x;
    const int sb = blockIdx.x;
    const int b  = blockIdx.y;
    const int nn = t & 63;
    const int qq = t >> 6;
    const int sw = 4 * (nn & 7);
    const int base = nn * QSTR;

    int L, k0, c0, npair, qoff4;
    const bool slot = decode_pair(t, L, k0, c0, npair, qoff4);
    const int c1 = c0 + ((npair == 2) ? 1 : 0);

    int qx[8];
    #pragma unroll
    for (int r = 0; r < 8; ++r) qx[r] = qoff4 ^ (4 * r);

    float a[4] = {0.f, 0.f, 0.f, 0.f};      // monomials (c0, L, k0..k0+3)
    float bq[4] = {0.f, 0.f, 0.f, 0.f};     // monomials (c1, L, k0..k0+3)
    const float* xb = x + (size_t)b * 3 * NPTS;

    for (int g = 0; g < GPB; ++g) {
        if (g) __syncthreads();
        {   // ---------------- phase A (identical to R11) ----------------
            const int n = (sb * GPB + g) * 64 + nn;
            const float x1 = xb[NPTS + n], x2 = xb[2 * NPTS + n];
            float T1r[16], T2r[16];
            T1r[0] = 1.f; T1r[1] = x1;
            #pragma unroll
            for (int k = 2; k < 16; ++k) T1r[k] = 2.f * x1 * T1r[k-1] - T1r[k-2];
            T2r[0] = 1.f; T2r[1] = x2;
            #pragma unroll
            for (int k = 2; k < 16; ++k) T2r[k] = 2.f * x2 * T2r[k-1] - T2r[k-2];

            #define QVAL(SS,E) (((E) <= (SS)) ? T1r[((SS)-(E)) & 15] * T2r[(E) & 15] : 0.f)
            #define ROWQ(SS, QO) { \
                _Pragma("unroll") \
                for (int blk2 = 0; blk2 < ((SS)+4)/4; ++blk2) { \
                    float4 v; \
                    v.x = QVAL(SS, 4*blk2+0); v.y = QVAL(SS, 4*blk2+1); \
                    v.z = QVAL(SS, 4*blk2+2); v.w = QVAL(SS, 4*blk2+3); \
                    *(float4*)&P[base + (((QO) + 4*blk2) ^ sw)] = v; } }

            if (qq == 0) {
                const float x0 = xb[n];
                float T0r[16];
                T0r[0] = 1.f; T0r[1] = x0;
                #pragma unroll
                for (int k = 2; k < 16; ++k) T0r[k] = 2.f * x0 * T0r[k-1] - T0r[k-2];
                #pragma unroll
                for (int cc = 0; cc < 16; ++cc)
                    P[T0OFF + cc * 64 + ((nn + 4 * cc) & 63)] = T0r[cc];
                ROWQ(0, 0)  ROWQ(1, 4)  ROWQ(2, 8)  ROWQ(3, 12)
            } else if (qq == 1) {
                ROWQ(4, 16) ROWQ(5, 24) ROWQ(6, 32) ROWQ(7, 40) ROWQ(8, 48)
            } else if (qq == 2) {
                ROWQ(9, 60) ROWQ(10, 72) ROWQ(11, 84) ROWQ(12, 96)
            } else {
                ROWQ(13, 112) ROWQ(14, 128) ROWQ(15, 144)
            }
            #undef ROWQ
            #undef QVAL
        }
        __syncthreads();

        // ---------------- phase B: paired-c accumulate ----------------
        if (slot) {
            #pragma unroll 4
            for (int q4 = 0; q4 < 16; ++q4) {
                const int np0 = q4 * 4;
                const float4 t0a =
                    *(const float4*)&P[T0OFF + c0 * 64 + ((np0 + 4 * c0) & 63)];
                const float4 t0b =
                    *(const float4*)&P[T0OFF + c1 * 64 + ((np0 + 4 * c1) & 63)];
                #pragma unroll
                for (int i = 0; i < 4; ++i) {
                    const int np = np0 + i;
                    const float4 qv = *(const float4*)&P[np * QSTR + qx[np & 7]];
                    const float ta = ((const float*)&t0a)[i];
                    const float tb = ((const float*)&t0b)[i];
                    a[0]  = fmaf(ta, qv.x, a[0]);
                    a[1]  = fmaf(ta, qv.y, a[1]);
                    a[2]  = fmaf(ta, qv.z, a[2]);
                    a[3]  = fmaf(ta, qv.w, a[3]);
                    bq[0] = fmaf(tb, qv.x, bq[0]);
                    bq[1] = fmaf(tb, qv.y, bq[1]);
                    bq[2] = fmaf(tb, qv.z, bq[2]);
                    bq[3] = fmaf(tb, qv.w, bq[3]);
                }
            }
        }
    }

    // store: m = tet(D)-1 + L(L+1)/2 + e2, consecutive in e2
    if (slot) {
        float* pb = part + ((size_t)b * NSPLIT + sb) * M_POLY;
        const int nv = (L - k0 + 1 < 4) ? (L - k0 + 1) : 4;
        {
            const int D  = c0 + L;
            const int mb = D * (D + 1) * (D + 2) / 6 - 1 + L * (L + 1) / 2;
            #pragma unroll
            for (int i = 0; i < 4; ++i)
                if (i < nv) pb[mb + k0 + i] = a[i];
        }
        if (npair == 2) {
            const int D  = c1 + L;
            const int mb = D * (D + 1) * (D + 2) / 6 - 1 + L * (L + 1) / 2;
            #pragma unroll
            for (int i = 0; i < 4; ++i)
                if (i < nv) pb[mb + k0 + i] = bq[i];
        }
    }
}

// ---------------------------------------------------------------------------
// Layer 1 — byte-identical to R11. grid (8, 32), block 512 = 64 o x 8 kg.
// ---------------------------------------------------------------------------
__global__ __launch_bounds__(512) void l1_kernel(
    const float* __restrict__ part,
    const float* __restrict__ W1, const float* __restrict__ b1,
    const float* __restrict__ g1, const float* __restrict__ be1,
    const float* __restrict__ rm1, const float* __restrict__ rv1,
    float* __restrict__ h1)
{
    __shared__ float fs[816];
    __shared__ float red[8][64];
    const int t  = threadIdx.x;
    const int og = blockIdx.x;
    const int b  = blockIdx.y;

    {
        float s0 = 0.f;
        #pragma unroll
        for (int sp = 0; sp < NSPLIT; ++sp)
            s0 += part[((size_t)b * NSPLIT + sp) * M_POLY + t];
        fs[t] = s0 * (1.0f / (float)NPTS);
        if (t < 303) {
            float s1 = 0.f;
            #pragma unroll
            for (int sp = 0; sp < NSPLIT; ++sp)
                s1 += part[((size_t)b * NSPLIT + sp) * M_POLY + 512 + t];
            fs[512 + t] = s1 * (1.0f / (float)NPTS);
        }
        if (t == 0) fs[815] = 0.f;
    }
    __syncthreads();

    const int o  = og * 64 + (t & 63);
    const int cg = t >> 6;
    const int kb = cg * 102;               // 8*102 = 816; fs[815]=0 nulls pad
    float acc = 0.f;
    #pragma unroll 6
    for (int kk = 0; kk < 102; ++kk) {
        const int k  = kb + kk;
        const int kr = (k < 815) ? k : 814;
        acc = fmaf(fs[k], W1[(size_t)kr * 512 + o], acc);
    }
    red[cg][t & 63] = acc;
    __syncthreads();

    if (t < 64) {
        float dot = 0.f;
        #pragma unroll
        for (int j = 0; j < 8; ++j) dot += red[j][t];
        const int oo = og * 64 + t;
        const float v = (dot + b1[oo] - rm1[oo]) * g1[oo] * rsqrtf(rv1[oo] + BN_EPS) + be1[oo];
        h1[b * 512 + oo] = v > 0.f ? v : 0.f;
    }
}

// ---------------------------------------------------------------------------
// Layer 2 — byte-identical to R11. grid (8, 32), block 512 = 32 o x 16 kg.
// ---------------------------------------------------------------------------
__global__ __launch_bounds__(512) void l2_kernel(
    const float* __restrict__ h1,
    const float* __restrict__ W2, const float* __restrict__ b2,
    const float* __restrict__ g2, const float* __restrict__ be2,
    const float* __restrict__ rm2, const float* __restrict__ rv2,
    float* __restrict__ h2)
{
    __shared__ float hs[512];
    __shared__ float red[16][32];
    const int t  = threadIdx.x;
    const int og = blockIdx.x;
    const int b  = blockIdx.y;

    hs[t] = h1[b * 512 + t];
    __syncthreads();

    const int o  = og * 32 + (t & 31);
    const int cg = t >> 5;
    const int kb = cg * 32;
    float acc = 0.f;
    #pragma unroll
    for (int kk = 0; kk < 32; ++kk)
        acc = fmaf(hs[kb + kk], W2[(size_t)(kb + kk) * 256 + o], acc);
    red[cg][t & 31] = acc;
    __syncthreads();

    if (t < 32) {
        float dot = 0.f;
        #pragma unroll
        for (int j = 0; j < 16; ++j) dot += red[j][t];
        const int oo = og * 32 + t;
        const float v = (dot + b2[oo] - rm2[oo]) * g2[oo] * rsqrtf(rv2[oo] + BN_EPS) + be2[oo];
        h2[b * 256 + oo] = v > 0.f ? v : 0.f;
    }
}

// ---------------------------------------------------------------------------
// Layers 3+4 — byte-identical to R11. grid = 32, block 512.
// ---------------------------------------------------------------------------
__global__ __launch_bounds__(512) void l34_kernel(
    const float* __restrict__ h2,
    const float* __restrict__ W3, const float* __restrict__ b3,
    const float* __restrict__ g3, const float* __restrict__ be3,
    const float* __restrict__ rm3, const float* __restrict__ rv3,
    const float* __restrict__ W4, const float* __restrict__ b4,
    float* __restrict__ out)
{
    __shared__ float hs[256];
    __shared__ float red3[4][128];
    __shared__ float h3s[128];
    __shared__ float red4[8][64];
    const int t = threadIdx.x;
    const int b = blockIdx.x;

    if (t < 256) hs[t] = h2[b * 256 + t];
    __syncthreads();

    {
        const int o  = t & 127;
        const int cg = t >> 7;
        const int kb = cg * 64;
        float acc = 0.f;
        #pragma unroll 8
        for (int kk = 0; kk < 64; ++kk)
            acc = fmaf(hs[kb + kk], W3[(size_t)(kb + kk) * 128 + o], acc);
        red3[cg][o] = acc;
    }
    __syncthreads();
    if (t < 128) {
        const float dot = red3[0][t] + red3[1][t] + red3[2][t] + red3[3][t];
        const float v = (dot + b3[t] - rm3[t]) * g3[t] * rsqrtf(rv3[t] + BN_EPS) + be3[t];
        h3s[t] = v > 0.f ? v : 0.f;
    }
    __syncthreads();

    {
        const int o  = t & 63;
        const int om = (o < 40) ? o : 39;
        const int cg = t >> 6;
        const int kb = cg * 16;
        float acc = 0.f;
        #pragma unroll
        for (int kk = 0; kk < 16; ++kk)
            acc = fmaf(h3s[kb + kk], W4[(size_t)(kb + kk) * 40 + om], acc);
        red4[cg][o] = acc;
    }
    __syncthreads();
    if (t < 40) {
        float dot = 0.f;
        #pragma unroll
        for (int j = 0; j < 8; ++j) dot += red4[j][t];
        out[b * 40 + t] = dot + b4[t];
    }
}

extern "C" void kernel_launch(void* const* d_in, const int* in_sizes, int n_in,
                              void* d_out, int out_size, void* d_ws, size_t ws_size,
                              hipStream_t stream) {
    const float* x  = (const float*)d_in[0];
    const float* W1 = (const float*)d_in[2];
    const float* b1 = (const float*)d_in[3];
    const float* g1 = (const float*)d_in[4];
    const float* be1= (const float*)d_in[5];
    const float* rm1= (const float*)d_in[6];
    const float* rv1= (const float*)d_in[7];
    const float* W2 = (const float*)d_in[8];
    const float* b2 = (const float*)d_in[9];
    const float* g2 = (const float*)d_in[10];
    const float* be2= (const float*)d_in[11];
    const float* rm2= (const float*)d_in[12];
    const float* rv2= (const float*)d_in[13];
    const float* W3 = (const float*)d_in[14];
    const float* b3 = (const float*)d_in[15];
    const float* g3 = (const float*)d_in[16];
    const float* be3= (const float*)d_in[17];
    const float* rm3= (const float*)d_in[18];
    const float* rv3= (const float*)d_in[19];
    const float* W4 = (const float*)d_in[20];
    const float* b4 = (const float*)d_in[21];
    float* out = (float*)d_out;

    float* part = (float*)d_ws;                              // 32*16*815 f32
    float* h1   = part + (size_t)BATCH * NSPLIT * M_POLY;    // 32*512
    float* h2   = h1 + (size_t)BATCH * 512;                  // 32*256

    moments_kernel<<<dim3(NSPLIT, BATCH), 256, 0, stream>>>(x, part);
    l1_kernel<<<dim3(8, BATCH), 512, 0, stream>>>(part,
        W1, b1, g1, be1, rm1, rv1, h1);
    l2_kernel<<<dim3(8, BATCH), 512, 0, stream>>>(h1,
        W2, b2, g2, be2, rm2, rv2, h2);
    l34_kernel<<<BATCH, 512, 0, stream>>>(h2,
        W3, b3, g3, be3, rm3, rv3, W4, b4, out);
}